// Round 4
// baseline (13655.025 us; speedup 1.0000x reference)
//
#include <hip/hip_runtime.h>
#include <cstdint>

#define NUM_CLASSES 20
#define KSEL 5
#define M_PTS 10000
#define C_DIM 256
#define HW 16384
#define NQ 64            // queries per block (1 per lane, shared by all 4 waves)
#define NJ 16            // j rows per round per wave
#define JCHUNK 2500      // j per wave (4 waves cover 10000)
#define NROUNDS 157      // ceil(2500/16)
#define INFV 1e30f

// Grid 512 x 256 threads. Block b: q = b*64 + lane. Wave w: j in [w*2500,(w+1)*2500).
// B tile is wave-private LDS [c][nj] -> compute reads are wave-uniform b128
// BROADCASTS (conflict-free); A is a coalesced 256B/wave global load per c
// (L2-resident). No __syncthreads in the main loop at all.
__global__ __launch_bounds__(256, 2) void knn_main(
    const float* __restrict__ x, const float* __restrict__ mx,
    const int* __restrict__ my, float* __restrict__ out)
{
  __shared__ union {
    struct { float Bs[4][C_DIM][NJ]; } m;                 // 64 KB, per-wave quarters
    struct { double Dd[4][NQ][KSEL]; int Dj[4][NQ][KSEL]; } e;  // 15.4 KB overlay
  } sm;
  __shared__ float mnS[4][NJ];

  const int t = threadIdx.x;
  const int w = t >> 6;
  const int l = t & 63;

  const int qflat = blockIdx.x * NQ + l;
  const int bb    = qflat >> 14;
  const int hw    = qflat & (HW - 1);
  const float* xq = x + (size_t)bb * C_DIM * HW + hw;    // x[c][q] at c*HW

  const int jw0 = w * JCHUNK;
  const int jwE = jw0 + JCHUNK;

  // staging role: lane stages row nj = l&15, c-chunk u = l>>4 -> [u*64, u*64+64)
  const int s_nj = l & 15;
  const int s_u  = l >> 4;

  float lv[KSEL]; int lj[KSEL]; float thr = INFV;
#pragma unroll
  for (int e = 0; e < KSEL; ++e) { lv[e] = INFV; lj[e] = 0x7fffffff; }

  float (*BsW)[NJ] = sm.m.Bs[w];

  // ---- prologue: load + stage round 0 ----
  float4 pf[16];
  {
    const int jr0 = jw0 + s_nj;
    const int jr  = (jr0 < jwE) ? jr0 : (jwE - 1);
    const float* src = mx + (size_t)jr * C_DIM + s_u * 64;
#pragma unroll
    for (int k = 0; k < 16; ++k) pf[k] = *(const float4*)(src + 4 * k);
  }
  {
    float nrm = 0.f;
#pragma unroll
    for (int k = 0; k < 16; ++k) {
      const int c = s_u * 64 + 4 * k;
      BsW[c + 0][s_nj] = pf[k].x; BsW[c + 1][s_nj] = pf[k].y;
      BsW[c + 2][s_nj] = pf[k].z; BsW[c + 3][s_nj] = pf[k].w;
      nrm = fmaf(pf[k].x, pf[k].x, nrm); nrm = fmaf(pf[k].y, pf[k].y, nrm);
      nrm = fmaf(pf[k].z, pf[k].z, nrm); nrm = fmaf(pf[k].w, pf[k].w, nrm);
    }
    nrm += __shfl_xor(nrm, 16);
    nrm += __shfl_xor(nrm, 32);
    if (l < 16) mnS[w][l] = (jw0 + l < jwE) ? nrm : INFV;
  }

  for (int r = 0; r < NROUNDS; ++r) {
    const int j0 = jw0 + r * NJ;

    // prefetch next round's 16 rows into regs (in flight under the c-loop)
    if (r + 1 < NROUNDS) {
      const int jr0 = j0 + NJ + s_nj;
      const int jr  = (jr0 < jwE) ? jr0 : (jwE - 1);
      const float* src = mx + (size_t)jr * C_DIM + s_u * 64;
#pragma unroll
      for (int k = 0; k < 16; ++k) pf[k] = *(const float4*)(src + 4 * k);
    }

    float acc[NJ];
#pragma unroll
    for (int n = 0; n < NJ; ++n) acc[n] = 0.f;

#pragma unroll 16
    for (int c = 0; c < C_DIM; ++c) {
      const float a = xq[(size_t)c * HW];                 // coalesced 256B/wave, L2-hit
      const float4 b0 = *(const float4*)&BsW[c][0];       // wave-uniform broadcasts
      const float4 b1 = *(const float4*)&BsW[c][4];
      const float4 b2 = *(const float4*)&BsW[c][8];
      const float4 b3 = *(const float4*)&BsW[c][12];
      acc[0]  = fmaf(a, b0.x, acc[0]);  acc[1]  = fmaf(a, b0.y, acc[1]);
      acc[2]  = fmaf(a, b0.z, acc[2]);  acc[3]  = fmaf(a, b0.w, acc[3]);
      acc[4]  = fmaf(a, b1.x, acc[4]);  acc[5]  = fmaf(a, b1.y, acc[5]);
      acc[6]  = fmaf(a, b1.z, acc[6]);  acc[7]  = fmaf(a, b1.w, acc[7]);
      acc[8]  = fmaf(a, b2.x, acc[8]);  acc[9]  = fmaf(a, b2.y, acc[9]);
      acc[10] = fmaf(a, b2.z, acc[10]); acc[11] = fmaf(a, b2.w, acc[11]);
      acc[12] = fmaf(a, b3.x, acc[12]); acc[13] = fmaf(a, b3.y, acc[13]);
      acc[14] = fmaf(a, b3.z, acc[14]); acc[15] = fmaf(a, b3.w, acc[15]);
    }

    // score = ||m||^2 - 2*dot (||x||^2 rank-invariant). Increasing-j arrival +
    // strict '<' == top_k lower-index tie-break. Invalid rows: mn=INF -> never insert.
#pragma unroll
    for (int n = 0; n < NJ; ++n) {
      const float sc = fmaf(-2.f, acc[n], mnS[w][n]);
      if (sc < thr) {
        const int jidx = j0 + n;
        const float v0 = lv[0], v1 = lv[1], v2 = lv[2], v3 = lv[3];
        const int   i0 = lj[0], i1 = lj[1], i2 = lj[2], i3 = lj[3];
        const bool c0 = sc < v0, c1 = sc < v1, c2 = sc < v2, c3 = sc < v3;
        lv[4] = c3 ? v3 : sc;             lj[4] = c3 ? i3 : jidx;
        lv[3] = c3 ? (c2 ? v2 : sc) : v3; lj[3] = c3 ? (c2 ? i2 : jidx) : i3;
        lv[2] = c2 ? (c1 ? v1 : sc) : v2; lj[2] = c2 ? (c1 ? i1 : jidx) : i2;
        lv[1] = c1 ? (c0 ? v0 : sc) : v1; lj[1] = c1 ? (c0 ? i0 : jidx) : i1;
        lv[0] = c0 ? sc : v0;             lj[0] = c0 ? jidx : i0;
        thr = lv[4];
      }
    }

    // stage round r+1 (regs -> LDS) + its norms; same-wave ordering, no barrier
    if (r + 1 < NROUNDS) {
      float nrm = 0.f;
#pragma unroll
      for (int k = 0; k < 16; ++k) {
        const int c = s_u * 64 + 4 * k;
        BsW[c + 0][s_nj] = pf[k].x; BsW[c + 1][s_nj] = pf[k].y;
        BsW[c + 2][s_nj] = pf[k].z; BsW[c + 3][s_nj] = pf[k].w;
        nrm = fmaf(pf[k].x, pf[k].x, nrm); nrm = fmaf(pf[k].y, pf[k].y, nrm);
        nrm = fmaf(pf[k].z, pf[k].z, nrm); nrm = fmaf(pf[k].w, pf[k].w, nrm);
      }
      nrm += __shfl_xor(nrm, 16);
      nrm += __shfl_xor(nrm, 32);
      if (l < 16) mnS[w][l] = (j0 + NJ + l < jwE) ? nrm : INFV;
    }
  }

  // ---- epilogue: per-wave fp64 re-rank of its own 5 candidates (regs only) ----
  double dd5[KSEL];
  {
    const float *m0 = mx + (size_t)lj[0] * C_DIM, *m1 = mx + (size_t)lj[1] * C_DIM;
    const float *m2 = mx + (size_t)lj[2] * C_DIM, *m3 = mx + (size_t)lj[3] * C_DIM;
    const float *m4 = mx + (size_t)lj[4] * C_DIM;
    double a0 = 0, a1 = 0, a2 = 0, a3 = 0, a4 = 0;
#pragma unroll 4
    for (int c = 0; c < C_DIM; ++c) {
      const double xv = (double)xq[(size_t)c * HW];
      double dd;
      dd = xv - (double)m0[c]; a0 = fma(dd, dd, a0);
      dd = xv - (double)m1[c]; a1 = fma(dd, dd, a1);
      dd = xv - (double)m2[c]; a2 = fma(dd, dd, a2);
      dd = xv - (double)m3[c]; a3 = fma(dd, dd, a3);
      dd = xv - (double)m4[c]; a4 = fma(dd, dd, a4);
    }
    dd5[0] = a0; dd5[1] = a1; dd5[2] = a2; dd5[3] = a3; dd5[4] = a4;
  }

  __syncthreads();            // all waves done with Bs -> overlay is safe
#pragma unroll
  for (int e = 0; e < KSEL; ++e) { sm.e.Dd[w][l][e] = dd5[e]; sm.e.Dj[w][l][e] = lj[e]; }
  __syncthreads();

  if (w == 0) {               // lane l finalizes query q = blockIdx*64 + l
    double dv[4 * KSEL]; int jv[4 * KSEL];
#pragma unroll
    for (int ww = 0; ww < 4; ++ww)
#pragma unroll
      for (int e = 0; e < KSEL; ++e) {
        dv[ww * KSEL + e] = sm.e.Dd[ww][l][e];
        jv[ww * KSEL + e] = sm.e.Dj[ww][l][e];
      }
    int labs[KSEL]; unsigned used = 0;
#pragma unroll
    for (int n = 0; n < KSEL; ++n) {
      double bd = 1e300; int bj = 0x7fffffff; int bk = 0;
#pragma unroll
      for (int k = 0; k < 4 * KSEL; ++k) {
        const bool avail = ((used >> k) & 1u) == 0u;
        if (avail && (dv[k] < bd || (dv[k] == bd && jv[k] < bj))) {
          bd = dv[k]; bj = jv[k]; bk = k;
        }
      }
      used |= (1u << bk);
      labs[n] = my[bj];
    }
    int bestLab = NUM_CLASSES, bestCnt = 0;
#pragma unroll
    for (int a = 0; a < KSEL; ++a) {
      int cnt = 0;
#pragma unroll
      for (int b2 = 0; b2 < KSEL; ++b2) cnt += (labs[b2] == labs[a]) ? 1 : 0;
      if (cnt > bestCnt || (cnt == bestCnt && labs[a] < bestLab)) {
        bestCnt = cnt; bestLab = labs[a];
      }
    }
    float* ob = out + (size_t)bb * NUM_CLASSES * HW + hw;
#pragma unroll
    for (int cls = 0; cls < NUM_CLASSES; ++cls)
      ob[(size_t)cls * HW] = (cls == bestLab) ? 1.0f : 0.0f;   // 256B/wave coalesced
  }
}

extern "C" void kernel_launch(void* const* d_in, const int* in_sizes, int n_in,
                              void* d_out, int out_size, void* d_ws, size_t ws_size,
                              hipStream_t stream) {
  (void)in_sizes; (void)n_in; (void)d_ws; (void)ws_size; (void)out_size;
  const float* x  = (const float*)d_in[0];
  const float* mx = (const float*)d_in[2];   // d_in[1] (y) unused by reference
  const int*   my = (const int*)d_in[3];
  float* out = (float*)d_out;
  knn_main<<<32768 / NQ, 256, 0, stream>>>(x, mx, my, out);
}

// Round 5
// 9429.772 us; speedup vs baseline: 1.4481x; 1.4481x over previous
//
#include <hip/hip_runtime.h>
#include <cstdint>

#define NUM_CLASSES 20
#define KSEL 5
#define M_PTS 10000
#define C_DIM 256
#define HW 16384
#define NQ 64            // queries per block: 1 per lane (same set for all 4 waves)
#define ASP 260          // As row pitch (floats): 65 f4-slots -> (l+k)%8 bank quads, conflict-free
#define JCHUNK 2500      // j rows per wave (4 waves cover 10000)
#define NJ 16            // j rows per group
#define NGRP 157         // ceil(2500/16)
#define INFV 1e30f

// Grid 512 x 256 threads (4 waves). Lane l of every wave owns query q=blk*64+l.
// Wave w sweeps j in [w*2500,(w+1)*2500). A-tile staged in LDS ONCE (one barrier),
// lane-private conflict-free b128 reads after that. B rows are wave-uniform ->
// compiler emits s_load into SGPRs (scalar pipe, no LDS, v_fma v,s,v).
// No barriers in the main loop.
__global__ __launch_bounds__(256, 2) void knn_main(
    const float* __restrict__ x, const float* __restrict__ mx,
    const int* __restrict__ my, float* __restrict__ out)
{
  __shared__ union {
    float As[NQ][ASP];                                         // 66.5 KB
    struct { double Dd[4][NQ][KSEL]; int Dj[4][NQ][KSEL]; } e; // 15.4 KB overlay
  } sm;

  const int t = threadIdx.x;
  const int w = t >> 6;
  const int l = t & 63;

  const int qflat = blockIdx.x * NQ;          // NQ divides HW -> no batch straddle
  const int bb    = qflat >> 14;
  const int hw0   = qflat & (HW - 1);
  const float* xbase = x + (size_t)bb * C_DIM * HW + hw0;   // x[c][q] at c*HW+q

  // ---- one-time A staging: thread t loads q=t&63, c = (t>>6)+4k (coalesced 256B) ----
  {
    const int q = t & 63;
    const int cb = t >> 6;
#pragma unroll 8
    for (int k = 0; k < 64; ++k) {
      const int c = cb + 4 * k;
      sm.As[q][c] = xbase[(size_t)c * HW + q];
    }
  }
  __syncthreads();                            // the only barrier before the epilogue

  const int jw0 = w * JCHUNK;
  const int jwE = jw0 + JCHUNK;

  float lv[KSEL]; int lj[KSEL]; float thr = INFV;
#pragma unroll
  for (int e = 0; e < KSEL; ++e) { lv[e] = INFV; lj[e] = 0x7fffffff; }

  const int nrow = l & 15;                    // norm duty: row l&15, c-seg (l>>4)*64
  const int nseg = (l >> 4) * 64;

  for (int jg = 0; jg < NGRP; ++jg) {
    const int j0 = jw0 + jg * NJ;

    // ---- group norms: lane computes 1/4 of one row, xor-reduce, keep in reg ----
    float nrm = 0.f;
    {
      int jr = j0 + nrow; jr = (jr < jwE) ? jr : (jwE - 1);
      const float4* src = (const float4*)(mx + (size_t)jr * C_DIM + nseg);
#pragma unroll
      for (int k = 0; k < 16; ++k) {
        const float4 v = src[k];
        nrm = fmaf(v.x, v.x, nrm); nrm = fmaf(v.y, v.y, nrm);
        nrm = fmaf(v.z, v.z, nrm); nrm = fmaf(v.w, v.w, nrm);
      }
      nrm += __shfl_xor(nrm, 16);
      nrm += __shfl_xor(nrm, 32);             // lanes {n,n+16,n+32,n+48} hold row n's norm
    }

    float acc[NJ];
#pragma unroll
    for (int n = 0; n < NJ; ++n) acc[n] = 0.f;

    for (int cc = 0; cc < 8; ++cc) {          // 32 c per chunk, rolled
      float a[32];
#pragma unroll
      for (int k = 0; k < 8; ++k)             // conflict-free lane-private b128
        *(float4*)&a[4 * k] = *(const float4*)&sm.As[l][cc * 32 + 4 * k];

#pragma unroll
      for (int jn = 0; jn < NJ; ++jn) {
        int jr = j0 + jn; jr = (jr < jwE) ? jr : (jwE - 1);           // uniform
        const float4* b4 = (const float4*)(mx + (size_t)jr * C_DIM + cc * 32);
#pragma unroll
        for (int k4 = 0; k4 < 8; ++k4) {
          const float4 bq = b4[k4];           // uniform addr -> s_load, SGPR operand
          acc[jn] = fmaf(a[4 * k4 + 0], bq.x, acc[jn]);
          acc[jn] = fmaf(a[4 * k4 + 1], bq.y, acc[jn]);
          acc[jn] = fmaf(a[4 * k4 + 2], bq.z, acc[jn]);
          acc[jn] = fmaf(a[4 * k4 + 3], bq.w, acc[jn]);
        }
      }
    }

    // ---- scoring: score = ||m||^2 - 2*dot; increasing-j + strict '<' == top_k tie-break ----
#pragma unroll
    for (int jn = 0; jn < NJ; ++jn) {
      float mnv = __shfl(nrm, jn);
      mnv = (j0 + jn < jwE) ? mnv : INFV;     // clamped duplicate rows never insert
      const float sc = fmaf(-2.f, acc[jn], mnv);
      if (sc < thr) {
        const int jidx = j0 + jn;
        const float v0 = lv[0], v1 = lv[1], v2 = lv[2], v3 = lv[3];
        const int   i0 = lj[0], i1 = lj[1], i2 = lj[2], i3 = lj[3];
        const bool c0 = sc < v0, c1 = sc < v1, c2 = sc < v2, c3 = sc < v3;
        lv[4] = c3 ? v3 : sc;             lj[4] = c3 ? i3 : jidx;
        lv[3] = c3 ? (c2 ? v2 : sc) : v3; lj[3] = c3 ? (c2 ? i2 : jidx) : i3;
        lv[2] = c2 ? (c1 ? v1 : sc) : v2; lj[2] = c2 ? (c1 ? i1 : jidx) : i2;
        lv[1] = c1 ? (c0 ? v0 : sc) : v1; lj[1] = c1 ? (c0 ? i0 : jidx) : i1;
        lv[0] = c0 ? sc : v0;             lj[0] = c0 ? jidx : i0;
        thr = lv[4];
      }
    }
  }

  // ---- epilogue: fp64 re-rank of own 5 (x from LDS), cross-wave merge, vote ----
  double dd5[KSEL];
  {
    const float *m0 = mx + (size_t)lj[0] * C_DIM, *m1 = mx + (size_t)lj[1] * C_DIM;
    const float *m2 = mx + (size_t)lj[2] * C_DIM, *m3 = mx + (size_t)lj[3] * C_DIM;
    const float *m4 = mx + (size_t)lj[4] * C_DIM;
    double a0 = 0, a1 = 0, a2 = 0, a3 = 0, a4 = 0;
#pragma unroll 4
    for (int c = 0; c < C_DIM; ++c) {
      const double xv = (double)sm.As[l][c];
      double dd;
      dd = xv - (double)m0[c]; a0 = fma(dd, dd, a0);
      dd = xv - (double)m1[c]; a1 = fma(dd, dd, a1);
      dd = xv - (double)m2[c]; a2 = fma(dd, dd, a2);
      dd = xv - (double)m3[c]; a3 = fma(dd, dd, a3);
      dd = xv - (double)m4[c]; a4 = fma(dd, dd, a4);
    }
    dd5[0] = a0; dd5[1] = a1; dd5[2] = a2; dd5[3] = a3; dd5[4] = a4;
  }

  __syncthreads();                            // all waves done with As -> overlay safe
#pragma unroll
  for (int e = 0; e < KSEL; ++e) { sm.e.Dd[w][l][e] = dd5[e]; sm.e.Dj[w][l][e] = lj[e]; }
  __syncthreads();

  if (w == 0) {                               // lane l finalizes query blk*64+l
    double dv[4 * KSEL]; int jv[4 * KSEL];
#pragma unroll
    for (int ww = 0; ww < 4; ++ww)
#pragma unroll
      for (int e = 0; e < KSEL; ++e) {
        dv[ww * KSEL + e] = sm.e.Dd[ww][l][e];
        jv[ww * KSEL + e] = sm.e.Dj[ww][l][e];
      }
    int labs[KSEL]; unsigned used = 0;
#pragma unroll
    for (int n = 0; n < KSEL; ++n) {
      double bd = 1e300; int bj = 0x7fffffff; int bk = 0;
#pragma unroll
      for (int k = 0; k < 4 * KSEL; ++k) {
        const bool avail = ((used >> k) & 1u) == 0u;
        if (avail && (dv[k] < bd || (dv[k] == bd && jv[k] < bj))) {
          bd = dv[k]; bj = jv[k]; bk = k;
        }
      }
      used |= (1u << bk);
      labs[n] = my[bj];
    }
    int bestLab = NUM_CLASSES, bestCnt = 0;
#pragma unroll
    for (int a = 0; a < KSEL; ++a) {
      int cnt = 0;
#pragma unroll
      for (int b2 = 0; b2 < KSEL; ++b2) cnt += (labs[b2] == labs[a]) ? 1 : 0;
      if (cnt > bestCnt || (cnt == bestCnt && labs[a] < bestLab)) {
        bestCnt = cnt; bestLab = labs[a];
      }
    }
    float* ob = out + (size_t)bb * NUM_CLASSES * HW + hw0 + l;
#pragma unroll
    for (int cls = 0; cls < NUM_CLASSES; ++cls)
      ob[(size_t)cls * HW] = (cls == bestLab) ? 1.0f : 0.0f;   // coalesced per plane
  }
}

extern "C" void kernel_launch(void* const* d_in, const int* in_sizes, int n_in,
                              void* d_out, int out_size, void* d_ws, size_t ws_size,
                              hipStream_t stream) {
  (void)in_sizes; (void)n_in; (void)d_ws; (void)ws_size; (void)out_size;
  const float* x  = (const float*)d_in[0];
  const float* mx = (const float*)d_in[2];   // d_in[1] (y) unused by reference
  const int*   my = (const int*)d_in[3];
  float* out = (float*)d_out;
  knn_main<<<32768 / NQ, 256, 0, stream>>>(x, mx, my, out);
}

// Round 6
// 859.613 us; speedup vs baseline: 15.8851x; 10.9698x over previous
//
#include <hip/hip_runtime.h>
#include <cstdint>

#define NUM_CLASSES 20
#define KSEL 5
#define M_PTS 10000
#define C_DIM 256
#define HW 16384
#define NQB 64          // queries per block (MFMA cols)
#define NJB 128         // j rows per tile (MFMA rows)
#define NT 79           // ceil(10000/128)
#define XP 264          // x_lds pitch (bf16): 132 dw -> row banks stride 4, 2-way max
#define MP 40           // m_lds pitch (bf16): 20 dw -> 2-way max
#define INFV 1e30f

typedef short short8 __attribute__((ext_vector_type(8)));   // 8 bf16 = 4 VGPR
typedef float f32x4 __attribute__((ext_vector_type(4)));

#define MFMA16(a, b, c) __builtin_amdgcn_mfma_f32_16x16x32_bf16(a, b, c, 0, 0, 0)

// RNE fp32->bf16, packed pair into u32 (low = first elem)
__device__ __forceinline__ uint pk2(float a, float b) {
  uint ua = __float_as_uint(a), ub = __float_as_uint(b);
  ua = (ua + 0x7fffu + ((ua >> 16) & 1u)) >> 16;
  ub = (ub + 0x7fffu + ((ub >> 16) & 1u)) >> 16;
  return (ua & 0xffffu) | (ub << 16);
}

// Grid 512 x 256 threads (4 waves: 2 j-halves x 2 q-halves).
// S[j][q] = sum_c m[j][c]*x[c][q] via mfma_f32_16x16x32_bf16:
//   A(m): lane supplies A[row=l&15][k=8*(l>>4)+e]; B(x): B[k=8*(l>>4)+e][col=l&15]
//   C/D: col=l&15, row=4*(l>>4)+reg   (guide §3, m89/m91-verified)
// score = ||m||^2 - 2*dot (fp32 norms, bf16 dot) -> per-lane reg top-5 ->
// per-query merge of 8 lists -> fp32 top-8 -> fp64 exact re-rank -> mode vote.
__global__ __launch_bounds__(256, 2) void knn_mfma(
    const float* __restrict__ x, const float* __restrict__ mx,
    const int* __restrict__ my, float* __restrict__ out)
{
  __shared__ union {
    struct {
      ushort xs[NQB][XP];     // 33792 B  x tile, bf16, staged once
      ushort ms[NJB][MP];     // 10240 B  m K-chunk, bf16, restaged per K-step
      float  mn[NJB];         // 512 B    fp32 row norms of current j-tile
    } m;
    struct {                  // epilogue overlay
      float Lv[NQB][8][KSEL];
      int   Lj[NQB][8][KSEL];
    } e;
  } sm;

  const int t  = threadIdx.x;
  const int w  = t >> 6;
  const int l  = t & 63;
  const int wj = w >> 1;        // j-half (64 rows)
  const int wq = w & 1;         // q-half (32 cols)
  const int lr = l & 15;
  const int lg = l >> 4;

  const int qflat = blockIdx.x * NQB;
  const int bb    = qflat >> 14;
  const int hw0   = qflat & (HW - 1);
  const float* xbase = x + (size_t)bb * C_DIM * HW + hw0;   // x[c][q] at c*HW+q

  // ---- stage x tile once: thread (q=t&63, pair-group t>>6), coalesced reads ----
  {
    const int q = t & 63;
    const int cpb = t >> 6;
#pragma unroll 8
    for (int k = 0; k < 32; ++k) {
      const int cp = cpb + 4 * k;                    // c-pair 0..127
      const float a0 = xbase[(size_t)(2 * cp) * HW + q];
      const float a1 = xbase[(size_t)(2 * cp + 1) * HW + q];
      ((uint*)&sm.m.xs[q][0])[cp] = pk2(a0, a1);
    }
  }

  float lv[2][KSEL]; int lj[2][KSEL]; float thr[2];
#pragma unroll
  for (int qf = 0; qf < 2; ++qf) {
    thr[qf] = INFV;
#pragma unroll
    for (int e = 0; e < KSEL; ++e) { lv[qf][e] = INFV; lj[qf][e] = 0x7fffffff; }
  }

  const int srow = t >> 1;        // staged m row 0..127
  const int sh   = t & 1;         // c-half (16 floats)

  for (int jt = 0; jt < NT; ++jt) {
    const int j0 = jt * NJB;
    f32x4 acc[4][2];
#pragma unroll
    for (int jf = 0; jf < 4; ++jf)
#pragma unroll
      for (int qf = 0; qf < 2; ++qf) acc[jf][qf] = (f32x4){0.f, 0.f, 0.f, 0.f};

    float np = 0.f;               // partial ||m||^2 over this thread's staged elems
    for (int ks = 0; ks < 8; ++ks) {
      // global m chunk -> regs (issued before barrier; latency overlaps drain)
      int jr = j0 + srow; jr = (jr < M_PTS) ? jr : (M_PTS - 1);
      const float4* src = (const float4*)(mx + (size_t)jr * C_DIM + ks * 32 + sh * 16);
      const float4 v0 = src[0], v1 = src[1], v2 = src[2], v3 = src[3];

      __syncthreads();            // prev K-step's LDS reads done (also covers x-stage @jt=0,ks=0)

      uint* dst = (uint*)&sm.m.ms[srow][sh * 16];
      dst[0] = pk2(v0.x, v0.y); dst[1] = pk2(v0.z, v0.w);
      dst[2] = pk2(v1.x, v1.y); dst[3] = pk2(v1.z, v1.w);
      dst[4] = pk2(v2.x, v2.y); dst[5] = pk2(v2.z, v2.w);
      dst[6] = pk2(v3.x, v3.y); dst[7] = pk2(v3.z, v3.w);
      np = fmaf(v0.x, v0.x, np); np = fmaf(v0.y, v0.y, np);
      np = fmaf(v0.z, v0.z, np); np = fmaf(v0.w, v0.w, np);
      np = fmaf(v1.x, v1.x, np); np = fmaf(v1.y, v1.y, np);
      np = fmaf(v1.z, v1.z, np); np = fmaf(v1.w, v1.w, np);
      np = fmaf(v2.x, v2.x, np); np = fmaf(v2.y, v2.y, np);
      np = fmaf(v2.z, v2.z, np); np = fmaf(v2.w, v2.w, np);
      np = fmaf(v3.x, v3.x, np); np = fmaf(v3.y, v3.y, np);
      np = fmaf(v3.z, v3.z, np); np = fmaf(v3.w, v3.w, np);
      if (ks == 7) {
        const float full = np + __shfl_xor(np, 1);   // t and t^1 share a row
        if (sh == 0) sm.m.mn[srow] = full;
      }
      __syncthreads();            // staging visible

      const short8 bq0 = *(const short8*)&sm.m.xs[wq * 32 + lr][ks * 32 + 8 * lg];
      const short8 bq1 = *(const short8*)&sm.m.xs[wq * 32 + 16 + lr][ks * 32 + 8 * lg];
#pragma unroll
      for (int jf = 0; jf < 4; ++jf) {
        const short8 af = *(const short8*)&sm.m.ms[wj * 64 + jf * 16 + lr][8 * lg];
        acc[jf][0] = MFMA16(af, bq0, acc[jf][0]);
        acc[jf][1] = MFMA16(af, bq1, acc[jf][1]);
      }
    }

    // selection (reads mn before next tile's ks=7 overwrites it; ms overwrite irrelevant)
#pragma unroll
    for (int jf = 0; jf < 4; ++jf) {
      const f32x4 mn4 = *(const f32x4*)&sm.m.mn[wj * 64 + jf * 16 + 4 * lg];
      const int jb = j0 + wj * 64 + jf * 16 + 4 * lg;
#pragma unroll
      for (int qf = 0; qf < 2; ++qf) {
#pragma unroll
        for (int e = 0; e < 4; ++e) {
          const int jg = jb + e;
          const float sc = fmaf(-2.f, acc[jf][qf][e], mn4[e]);
          if (jg < M_PTS && sc < thr[qf]) {     // ascending-j + strict '<' == top_k tie-break
            const float v0 = lv[qf][0], v1 = lv[qf][1], v2 = lv[qf][2], v3 = lv[qf][3];
            const int   i0 = lj[qf][0], i1 = lj[qf][1], i2 = lj[qf][2], i3 = lj[qf][3];
            const bool c0 = sc < v0, c1 = sc < v1, c2 = sc < v2, c3 = sc < v3;
            lv[qf][4] = c3 ? v3 : sc;             lj[qf][4] = c3 ? i3 : jg;
            lv[qf][3] = c3 ? (c2 ? v2 : sc) : v3; lj[qf][3] = c3 ? (c2 ? i2 : jg) : i3;
            lv[qf][2] = c2 ? (c1 ? v1 : sc) : v2; lj[qf][2] = c2 ? (c1 ? i1 : jg) : i2;
            lv[qf][1] = c1 ? (c0 ? v0 : sc) : v1; lj[qf][1] = c1 ? (c0 ? i0 : jg) : i1;
            lv[qf][0] = c0 ? sc : v0;             lj[qf][0] = c0 ? jg : i0;
            thr[qf] = lv[qf][4];
          }
        }
      }
    }
  }

  // ---- epilogue ----
  __syncthreads();                // main loop done -> overlay safe
#pragma unroll
  for (int qf = 0; qf < 2; ++qf) {
    const int q = wq * 32 + qf * 16 + lr;
    const int s = wj * 4 + lg;
#pragma unroll
    for (int e = 0; e < KSEL; ++e) { sm.e.Lv[q][s][e] = lv[qf][e]; sm.e.Lj[q][s][e] = lj[qf][e]; }
  }
  __syncthreads();

  if (t < NQB) {                  // thread t finalizes query qflat + t
    float bv[8]; int bj2[8];
#pragma unroll
    for (int k = 0; k < 8; ++k) { bv[k] = INFV; bj2[k] = 0x7fffffff; }
    for (int s = 0; s < 8; ++s) {
#pragma unroll
      for (int e = 0; e < KSEL; ++e) {
        const float v = sm.e.Lv[t][s][e];
        const int  j = sm.e.Lj[t][s][e];
        if (v < bv[7] || (v == bv[7] && j < bj2[7])) {
          int pos = 7;
          while (pos > 0 && (bv[pos - 1] > v || (bv[pos - 1] == v && bj2[pos - 1] > j))) {
            bv[pos] = bv[pos - 1]; bj2[pos] = bj2[pos - 1]; --pos;
          }
          bv[pos] = v; bj2[pos] = j;
        }
      }
    }
    // fp64 exact distances for 8 candidates (x fp32 from global, coalesced across t)
    const float *m0 = mx + (size_t)bj2[0] * C_DIM, *m1 = mx + (size_t)bj2[1] * C_DIM;
    const float *m2 = mx + (size_t)bj2[2] * C_DIM, *m3 = mx + (size_t)bj2[3] * C_DIM;
    const float *m4 = mx + (size_t)bj2[4] * C_DIM, *m5 = mx + (size_t)bj2[5] * C_DIM;
    const float *m6 = mx + (size_t)bj2[6] * C_DIM, *m7 = mx + (size_t)bj2[7] * C_DIM;
    const float* xq = xbase + t;
    double d0 = 0, d1 = 0, d2 = 0, d3 = 0, d4 = 0, d5 = 0, d6 = 0, d7 = 0;
#pragma unroll 4
    for (int c = 0; c < C_DIM; ++c) {
      const double xv = (double)xq[(size_t)c * HW];
      double dd;
      dd = xv - (double)m0[c]; d0 = fma(dd, dd, d0);
      dd = xv - (double)m1[c]; d1 = fma(dd, dd, d1);
      dd = xv - (double)m2[c]; d2 = fma(dd, dd, d2);
      dd = xv - (double)m3[c]; d3 = fma(dd, dd, d3);
      dd = xv - (double)m4[c]; d4 = fma(dd, dd, d4);
      dd = xv - (double)m5[c]; d5 = fma(dd, dd, d5);
      dd = xv - (double)m6[c]; d6 = fma(dd, dd, d6);
      dd = xv - (double)m7[c]; d7 = fma(dd, dd, d7);
    }
    const double dv[8] = {d0, d1, d2, d3, d4, d5, d6, d7};
    const int    jv[8] = {bj2[0], bj2[1], bj2[2], bj2[3], bj2[4], bj2[5], bj2[6], bj2[7]};
    int labs[KSEL]; unsigned used = 0;
#pragma unroll
    for (int n = 0; n < KSEL; ++n) {
      double bd = 1e300; int bj = 0x7fffffff; int bk = 0;
#pragma unroll
      for (int k = 0; k < 8; ++k) {
        const bool avail = ((used >> k) & 1u) == 0u;
        if (avail && (dv[k] < bd || (dv[k] == bd && jv[k] < bj))) {
          bd = dv[k]; bj = jv[k]; bk = k;
        }
      }
      used |= (1u << bk);
      labs[n] = my[bj];
    }
    int bestLab = NUM_CLASSES, bestCnt = 0;
#pragma unroll
    for (int a = 0; a < KSEL; ++a) {
      int cnt = 0;
#pragma unroll
      for (int b2 = 0; b2 < KSEL; ++b2) cnt += (labs[b2] == labs[a]) ? 1 : 0;
      if (cnt > bestCnt || (cnt == bestCnt && labs[a] < bestLab)) {
        bestCnt = cnt; bestLab = labs[a];
      }
    }
    float* ob = out + (size_t)bb * NUM_CLASSES * HW + hw0 + t;
#pragma unroll
    for (int cls = 0; cls < NUM_CLASSES; ++cls)
      ob[(size_t)cls * HW] = (cls == bestLab) ? 1.0f : 0.0f;   // coalesced per plane
  }
}

extern "C" void kernel_launch(void* const* d_in, const int* in_sizes, int n_in,
                              void* d_out, int out_size, void* d_ws, size_t ws_size,
                              hipStream_t stream) {
  (void)in_sizes; (void)n_in; (void)d_ws; (void)ws_size; (void)out_size;
  const float* x  = (const float*)d_in[0];
  const float* mx = (const float*)d_in[2];   // d_in[1] (y) unused by reference
  const int*   my = (const int*)d_in[3];
  float* out = (float*)d_out;
  knn_mfma<<<32768 / NQB, 256, 0, stream>>>(x, mx, my, out);
}

// Round 8
// 562.347 us; speedup vs baseline: 24.2822x; 1.5286x over previous
//
#include <hip/hip_runtime.h>
#include <cstdint>

#define NUM_CLASSES 20
#define KSEL 5
#define M_PTS 10000
#define C_DIM 256
#define HW 16384
#define NQB 128          // queries per block
#define NJB 128          // j rows per tile
#define NT 79            // ceil(10000/128); 79*128 = 10112
#define MPAD 10112
#define INFV 1e30f

// ws layout (bytes)
#define WS_MN_OFF 0                      // float mn[10112]          = 40448 B
#define WS_MW_OFF 40448u                 // ushort mw[10000*256]     = 5120000 B
#define WS_XB_OFF 5160448u               // ushort xb[32768*256]     = 16777216 B
#define WS_TOTAL  21937664u

typedef short short8 __attribute__((ext_vector_type(8)));
typedef float f32x4 __attribute__((ext_vector_type(4)));

#define MFMA16(a, b, c) __builtin_amdgcn_mfma_f32_16x16x32_bf16(a, b, c, 0, 0, 0)

__device__ __forceinline__ uint pk2(float a, float b) {   // RNE f32->bf16 pair
  uint ua = __float_as_uint(a), ub = __float_as_uint(b);
  ua = (ua + 0x7fffu + ((ua >> 16) & 1u)) >> 16;
  ub = (ub + 0x7fffu + ((ub >> 16) & 1u)) >> 16;
  return (ua & 0xffffu) | (ub << 16);
}

__device__ __forceinline__ void gl16(const ushort* g, ushort* l) {
  __builtin_amdgcn_global_load_lds(
      (const __attribute__((address_space(1))) uint*)g,
      (__attribute__((address_space(3))) uint*)l, 16, 0, 0);
}

// ---- prep 1: m -> bf16 rows + fp32 norms (INF for padded rows) ----
__global__ void conv_m(const float* __restrict__ mx, ushort* __restrict__ mw,
                       float* __restrict__ mn) {
  const int t = threadIdx.x;
  const int r = blockIdx.x * 64 + (t >> 2);
  const int sg = t & 3;
  if (r >= MPAD) return;
  if (r >= M_PTS) { if (sg == 0) mn[r] = INFV; return; }
  const float4* src = (const float4*)(mx + (size_t)r * C_DIM + sg * 64);
  float4 v[16];
#pragma unroll
  for (int k = 0; k < 16; ++k) v[k] = src[k];
  uint u[32];
  float np = 0.f;
#pragma unroll
  for (int k = 0; k < 16; ++k) {
    u[2 * k]     = pk2(v[k].x, v[k].y);
    u[2 * k + 1] = pk2(v[k].z, v[k].w);
    np = fmaf(v[k].x, v[k].x, np); np = fmaf(v[k].y, v[k].y, np);
    np = fmaf(v[k].z, v[k].z, np); np = fmaf(v[k].w, v[k].w, np);
  }
  uint4* dst = (uint4*)(mw + (size_t)r * C_DIM + sg * 64);
#pragma unroll
  for (int i = 0; i < 8; ++i) dst[i] = *(const uint4*)&u[4 * i];
  np += __shfl_xor(np, 1);
  np += __shfl_xor(np, 2);
  if (sg == 0) mn[r] = np;
}

// ---- prep 2: x[b][c][hw] -> xb[n][c] bf16 (n = b*16384 + hw) ----
__global__ void conv_x(const float* __restrict__ x, ushort* __restrict__ xb) {
  const int t = threadIdx.x;
  const int n = blockIdx.x * 64 + (t & 63);
  const int seg = t >> 6;                      // c range [seg*64, seg*64+64)
  const int bb = n >> 14, hw = n & (HW - 1);
  const float* src = x + (size_t)bb * C_DIM * HW + hw;
  uint u[32];
#pragma unroll 8
  for (int k = 0; k < 32; ++k) {
    const int c = seg * 64 + 2 * k;
    const float a0 = src[(size_t)c * HW];      // coalesced across lanes
    const float a1 = src[(size_t)(c + 1) * HW];
    u[k] = pk2(a0, a1);
  }
  uint4* dst = (uint4*)(xb + (size_t)n * C_DIM + seg * 64);
#pragma unroll
  for (int i = 0; i < 8; ++i) dst[i] = *(const uint4*)&u[4 * i];
}

// ---- main: 256 blocks x 512 thr (8 waves: wj 0..3 x wq 0..1).
// Per tile: barrier -> 8 global_load_lds/wave (linear dest, XOR-swizzled src:
// phys slot = kslot ^ (row&7)) -> barrier -> 8 K-steps of {2 ds_read_b128 + 8 MFMA}.
// B(x) frags live in 128 VGPRs, loaded once from precomputed xb. m97-proven sync.
__global__ __launch_bounds__(512, 2) void knn_big(
    const float* __restrict__ x, const float* __restrict__ mx,
    const ushort* __restrict__ mw, const float* __restrict__ mn,
    const ushort* __restrict__ xb, const int* __restrict__ my,
    float* __restrict__ out)
{
  __shared__ union {
    ushort As[NJB][C_DIM];                                        // 64 KB
    struct { float Lv[64][16][KSEL]; int Lj[64][16][KSEL]; } e;   // 40 KB overlay
  } sm;

  const int t  = threadIdx.x;
  const int w  = t >> 6;
  const int l  = t & 63;
  const int wj = w >> 1;        // row block: wj*32 .. +32
  const int wq = w & 1;         // col block: wq*64 .. +64
  const int lr = l & 15;
  const int lg = l >> 4;

  const int q0  = blockIdx.x * NQB;
  const int bb  = q0 >> 14;
  const int hw0 = q0 & (HW - 1);

  // ---- B fragments in registers: 4 qf x 8 ks (128 VGPR), loaded once ----
  short8 bq[4][8];
#pragma unroll
  for (int qf = 0; qf < 4; ++qf) {
    const ushort* xrow = xb + (size_t)(q0 + wq * 64 + qf * 16 + lr) * C_DIM;
#pragma unroll
    for (int ks = 0; ks < 8; ++ks)
      bq[qf][ks] = *(const short8*)(xrow + ks * 32 + lg * 8);
  }

  float lv[4][KSEL]; int lj[4][KSEL]; float thr[4];
#pragma unroll
  for (int qf = 0; qf < 4; ++qf) {
    thr[qf] = INFV;
#pragma unroll
    for (int e = 0; e < KSEL; ++e) { lv[qf][e] = INFV; lj[qf][e] = 0x7fffffff; }
  }

  const int s_s    = l & 31;    // dest slot within a row-pair
  const int s_rsub = l >> 5;    // 0/1: which row of the pair

  const int br0 = wj * 32 + lr;           // A-frag rows (tile-local)
  const int br1 = br0 + 16;
  const int xr  = lr & 7;                 // XOR key (same for br0/br1: 32,16 = 0 mod 8)

  for (int jt = 0; jt < NT; ++jt) {
    const int j0 = jt * NJB;

    __syncthreads();                      // prev tile's LDS reads done (WAR guard)
#pragma unroll
    for (int i = 0; i < 8; ++i) {         // wave w stages rows w*16 .. w*16+15
      const int row = w * 16 + 2 * i + s_rsub;
      int jr = j0 + row; if (jr >= M_PTS) jr = M_PTS - 1;
      gl16(mw + (size_t)jr * C_DIM + ((s_s ^ (row & 7)) * 8),
           &sm.As[w * 16 + 2 * i][0]);    // dest: wave-uniform base + lane*16 (linear)
    }
    __syncthreads();                      // vmcnt(0) drain at barrier -> stages landed

    const f32x4 mnr0 = *(const f32x4*)(mn + j0 + wj * 32 + 4 * lg);
    const f32x4 mnr1 = *(const f32x4*)(mn + j0 + wj * 32 + 16 + 4 * lg);

    f32x4 acc[2][4];
#pragma unroll
    for (int jf = 0; jf < 2; ++jf)
#pragma unroll
      for (int qf = 0; qf < 4; ++qf) acc[jf][qf] = (f32x4){0.f, 0.f, 0.f, 0.f};

#pragma unroll
    for (int ks = 0; ks < 8; ++ks) {
      const int k0 = ks * 4 + lg;         // logical k-slot
      const short8 af0 = *(const short8*)&sm.As[br0][(k0 ^ xr) * 8];  // 2-way max
      const short8 af1 = *(const short8*)&sm.As[br1][(k0 ^ xr) * 8];
#pragma unroll
      for (int qf = 0; qf < 4; ++qf) {
        acc[0][qf] = MFMA16(af0, bq[qf][ks], acc[0][qf]);
        acc[1][qf] = MFMA16(af1, bq[qf][ks], acc[1][qf]);
      }
    }

    // selection: score = ||m||^2 - 2*dot; ascending-j + strict '<' == top_k tie-break.
#pragma unroll
    for (int jf = 0; jf < 2; ++jf) {
      const f32x4 mn4 = (jf == 0) ? mnr0 : mnr1;
      const int jb = j0 + wj * 32 + jf * 16 + 4 * lg;
#pragma unroll
      for (int qf = 0; qf < 4; ++qf) {
#pragma unroll
        for (int e = 0; e < 4; ++e) {
          const int jg = jb + e;
          const float sc = fmaf(-2.f, acc[jf][qf][e], mn4[e]);
          if (jg < M_PTS && sc < thr[qf]) {
            const float v0 = lv[qf][0], v1 = lv[qf][1], v2 = lv[qf][2], v3 = lv[qf][3];
            const int   i0 = lj[qf][0], i1 = lj[qf][1], i2 = lj[qf][2], i3 = lj[qf][3];
            const bool c0 = sc < v0, c1 = sc < v1, c2 = sc < v2, c3 = sc < v3;
            lv[qf][4] = c3 ? v3 : sc;             lj[qf][4] = c3 ? i3 : jg;
            lv[qf][3] = c3 ? (c2 ? v2 : sc) : v3; lj[qf][3] = c3 ? (c2 ? i2 : jg) : i3;
            lv[qf][2] = c2 ? (c1 ? v1 : sc) : v2; lj[qf][2] = c2 ? (c1 ? i1 : jg) : i2;
            lv[qf][1] = c1 ? (c0 ? v0 : sc) : v1; lj[qf][1] = c1 ? (c0 ? i0 : jg) : i1;
            lv[qf][0] = c0 ? sc : v0;             lj[qf][0] = c0 ? jg : i0;
            thr[qf] = lv[qf][4];
          }
        }
      }
    }
  }

  // ---- epilogue: two passes of 64 queries (40 KB overlay). wq==pass waves own them. ----
#pragma unroll
  for (int pass = 0; pass < 2; ++pass) {
    __syncthreads();                      // As reads / prev merge done
    if (wq == pass) {
#pragma unroll
      for (int qf = 0; qf < 4; ++qf) {
        const int ql = qf * 16 + lr;      // query - pass*64, in [0,64)
        const int s  = wj * 4 + lg;       // 16 lists per query
#pragma unroll
        for (int e = 0; e < KSEL; ++e) { sm.e.Lv[ql][s][e] = lv[qf][e]; sm.e.Lj[ql][s][e] = lj[qf][e]; }
      }
    }
    __syncthreads();

    if (t < 64) {                         // thread t finalizes query q0 + pass*64 + t
      float bv[8]; int bj2[8];
#pragma unroll
      for (int k = 0; k < 8; ++k) { bv[k] = INFV; bj2[k] = 0x7fffffff; }
      for (int s = 0; s < 16; ++s) {
#pragma unroll
        for (int e = 0; e < KSEL; ++e) {
          const float v = sm.e.Lv[t][s][e];
          const int  j = sm.e.Lj[t][s][e];
          if (v < bv[7] || (v == bv[7] && j < bj2[7])) {
            int pos = 7;
            while (pos > 0 && (bv[pos - 1] > v || (bv[pos - 1] == v && bj2[pos - 1] > j))) {
              bv[pos] = bv[pos - 1]; bj2[pos] = bj2[pos - 1]; --pos;
            }
            bv[pos] = v; bj2[pos] = j;
          }
        }
      }
      const float *m0 = mx + (size_t)bj2[0] * C_DIM, *m1 = mx + (size_t)bj2[1] * C_DIM;
      const float *m2 = mx + (size_t)bj2[2] * C_DIM, *m3 = mx + (size_t)bj2[3] * C_DIM;
      const float *m4 = mx + (size_t)bj2[4] * C_DIM, *m5 = mx + (size_t)bj2[5] * C_DIM;
      const float *m6 = mx + (size_t)bj2[6] * C_DIM, *m7 = mx + (size_t)bj2[7] * C_DIM;
      const float* xq = x + (size_t)bb * C_DIM * HW + hw0 + pass * 64 + t;
      double d0 = 0, d1 = 0, d2 = 0, d3 = 0, d4 = 0, d5 = 0, d6 = 0, d7 = 0;
#pragma unroll 4
      for (int c = 0; c < C_DIM; ++c) {
        const double xv = (double)xq[(size_t)c * HW];
        double dd;
        dd = xv - (double)m0[c]; d0 = fma(dd, dd, d0);
        dd = xv - (double)m1[c]; d1 = fma(dd, dd, d1);
        dd = xv - (double)m2[c]; d2 = fma(dd, dd, d2);
        dd = xv - (double)m3[c]; d3 = fma(dd, dd, d3);
        dd = xv - (double)m4[c]; d4 = fma(dd, dd, d4);
        dd = xv - (double)m5[c]; d5 = fma(dd, dd, d5);
        dd = xv - (double)m6[c]; d6 = fma(dd, dd, d6);
        dd = xv - (double)m7[c]; d7 = fma(dd, dd, d7);
      }
      const double dv[8] = {d0, d1, d2, d3, d4, d5, d6, d7};
      const int    jvv[8] = {bj2[0], bj2[1], bj2[2], bj2[3], bj2[4], bj2[5], bj2[6], bj2[7]};
      int labs[KSEL]; unsigned used = 0;
#pragma unroll
      for (int n = 0; n < KSEL; ++n) {
        double bd = 1e300; int bj = 0x7fffffff; int bk = 0;
#pragma unroll
        for (int k = 0; k < 8; ++k) {
          const bool avail = ((used >> k) & 1u) == 0u;
          if (avail && (dv[k] < bd || (dv[k] == bd && jvv[k] < bj))) {
            bd = dv[k]; bj = jvv[k]; bk = k;
          }
        }
        used |= (1u << bk);
        labs[n] = my[bj];
      }
      int bestLab = NUM_CLASSES, bestCnt = 0;
#pragma unroll
      for (int a = 0; a < KSEL; ++a) {
        int cnt = 0;
#pragma unroll
        for (int b2 = 0; b2 < KSEL; ++b2) cnt += (labs[b2] == labs[a]) ? 1 : 0;
        if (cnt > bestCnt || (cnt == bestCnt && labs[a] < bestLab)) {
          bestCnt = cnt; bestLab = labs[a];
        }
      }
      float* ob = out + (size_t)bb * NUM_CLASSES * HW + hw0 + pass * 64 + t;
#pragma unroll
      for (int cls = 0; cls < NUM_CLASSES; ++cls)
        ob[(size_t)cls * HW] = (cls == bestLab) ? 1.0f : 0.0f;
    }
  }
}

// ================= fallback (round-6 kernel, proven): used if ws too small ========
#define FNQB 64
#define FNJB 128
#define FNT 79
#define FXP 264
#define FMP 40
__global__ __launch_bounds__(256, 2) void knn_fb(
    const float* __restrict__ x, const float* __restrict__ mx,
    const int* __restrict__ my, float* __restrict__ out)
{
  __shared__ union {
    struct { ushort xs[FNQB][FXP]; ushort ms[FNJB][FMP]; float mnv[FNJB]; } m;
    struct { float Lv[FNQB][8][KSEL]; int Lj[FNQB][8][KSEL]; } e;
  } sm;
  const int t = threadIdx.x, w = t >> 6, l = t & 63;
  const int wj = w >> 1, wq = w & 1, lr = l & 15, lg = l >> 4;
  const int qflat = blockIdx.x * FNQB, bb = qflat >> 14, hw0 = qflat & (HW - 1);
  const float* xbase = x + (size_t)bb * C_DIM * HW + hw0;
  {
    const int q = t & 63, cpb = t >> 6;
#pragma unroll 8
    for (int k = 0; k < 32; ++k) {
      const int cp = cpb + 4 * k;
      ((uint*)&sm.m.xs[q][0])[cp] =
          pk2(xbase[(size_t)(2 * cp) * HW + q], xbase[(size_t)(2 * cp + 1) * HW + q]);
    }
  }
  float lv[2][KSEL]; int lj[2][KSEL]; float thr[2];
#pragma unroll
  for (int qf = 0; qf < 2; ++qf) {
    thr[qf] = INFV;
#pragma unroll
    for (int e = 0; e < KSEL; ++e) { lv[qf][e] = INFV; lj[qf][e] = 0x7fffffff; }
  }
  const int srow = t >> 1, sh = t & 1;
  for (int jt = 0; jt < FNT; ++jt) {
    const int j0 = jt * FNJB;
    f32x4 acc[4][2];
#pragma unroll
    for (int jf = 0; jf < 4; ++jf)
#pragma unroll
      for (int qf = 0; qf < 2; ++qf) acc[jf][qf] = (f32x4){0.f, 0.f, 0.f, 0.f};
    float np = 0.f;
    for (int ks = 0; ks < 8; ++ks) {
      int jr = j0 + srow; jr = (jr < M_PTS) ? jr : (M_PTS - 1);
      const float4* src = (const float4*)(mx + (size_t)jr * C_DIM + ks * 32 + sh * 16);
      const float4 v0 = src[0], v1 = src[1], v2 = src[2], v3 = src[3];
      __syncthreads();
      uint* dst = (uint*)&sm.m.ms[srow][sh * 16];
      dst[0] = pk2(v0.x, v0.y); dst[1] = pk2(v0.z, v0.w);
      dst[2] = pk2(v1.x, v1.y); dst[3] = pk2(v1.z, v1.w);
      dst[4] = pk2(v2.x, v2.y); dst[5] = pk2(v2.z, v2.w);
      dst[6] = pk2(v3.x, v3.y); dst[7] = pk2(v3.z, v3.w);
      np = fmaf(v0.x, v0.x, np); np = fmaf(v0.y, v0.y, np);
      np = fmaf(v0.z, v0.z, np); np = fmaf(v0.w, v0.w, np);
      np = fmaf(v1.x, v1.x, np); np = fmaf(v1.y, v1.y, np);
      np = fmaf(v1.z, v1.z, np); np = fmaf(v1.w, v1.w, np);
      np = fmaf(v2.x, v2.x, np); np = fmaf(v2.y, v2.y, np);
      np = fmaf(v2.z, v2.z, np); np = fmaf(v2.w, v2.w, np);
      np = fmaf(v3.x, v3.x, np); np = fmaf(v3.y, v3.y, np);
      np = fmaf(v3.z, v3.z, np); np = fmaf(v3.w, v3.w, np);
      if (ks == 7) {
        const float full = np + __shfl_xor(np, 1);
        if (sh == 0) sm.m.mnv[srow] = full;
      }
      __syncthreads();
      const short8 bq0 = *(const short8*)&sm.m.xs[wq * 32 + lr][ks * 32 + 8 * lg];
      const short8 bq1 = *(const short8*)&sm.m.xs[wq * 32 + 16 + lr][ks * 32 + 8 * lg];
#pragma unroll
      for (int jf = 0; jf < 4; ++jf) {
        const short8 af = *(const short8*)&sm.m.ms[wj * 64 + jf * 16 + lr][8 * lg];
        acc[jf][0] = MFMA16(af, bq0, acc[jf][0]);
        acc[jf][1] = MFMA16(af, bq1, acc[jf][1]);
      }
    }
#pragma unroll
    for (int jf = 0; jf < 4; ++jf) {
      const f32x4 mn4 = *(const f32x4*)&sm.m.mnv[wj * 64 + jf * 16 + 4 * lg];
      const int jb = j0 + wj * 64 + jf * 16 + 4 * lg;
#pragma unroll
      for (int qf = 0; qf < 2; ++qf) {
#pragma unroll
        for (int e = 0; e < 4; ++e) {
          const int jg = jb + e;
          const float sc = fmaf(-2.f, acc[jf][qf][e], mn4[e]);
          if (jg < M_PTS && sc < thr[qf]) {
            const float v0 = lv[qf][0], v1 = lv[qf][1], v2 = lv[qf][2], v3 = lv[qf][3];
            const int   i0 = lj[qf][0], i1 = lj[qf][1], i2 = lj[qf][2], i3 = lj[qf][3];
            const bool c0 = sc < v0, c1 = sc < v1, c2 = sc < v2, c3 = sc < v3;
            lv[qf][4] = c3 ? v3 : sc;             lj[qf][4] = c3 ? i3 : jg;
            lv[qf][3] = c3 ? (c2 ? v2 : sc) : v3; lj[qf][3] = c3 ? (c2 ? i2 : jg) : i3;
            lv[qf][2] = c2 ? (c1 ? v1 : sc) : v2; lj[qf][2] = c2 ? (c1 ? i1 : jg) : i2;
            lv[qf][1] = c1 ? (c0 ? v0 : sc) : v1; lj[qf][1] = c1 ? (c0 ? i0 : jg) : i1;
            lv[qf][0] = c0 ? sc : v0;             lj[qf][0] = c0 ? jg : i0;
            thr[qf] = lv[qf][4];
          }
        }
      }
    }
  }
  __syncthreads();
#pragma unroll
  for (int qf = 0; qf < 2; ++qf) {
    const int q = wq * 32 + qf * 16 + lr, s = wj * 4 + lg;
#pragma unroll
    for (int e = 0; e < KSEL; ++e) { sm.e.Lv[q][s][e] = lv[qf][e]; sm.e.Lj[q][s][e] = lj[qf][e]; }
  }
  __syncthreads();
  if (t < FNQB) {
    float bv[8]; int bj2[8];
#pragma unroll
    for (int k = 0; k < 8; ++k) { bv[k] = INFV; bj2[k] = 0x7fffffff; }
    for (int s = 0; s < 8; ++s) {
#pragma unroll
      for (int e = 0; e < KSEL; ++e) {
        const float v = sm.e.Lv[t][s][e]; const int j = sm.e.Lj[t][s][e];
        if (v < bv[7] || (v == bv[7] && j < bj2[7])) {
          int pos = 7;
          while (pos > 0 && (bv[pos - 1] > v || (bv[pos - 1] == v && bj2[pos - 1] > j))) {
            bv[pos] = bv[pos - 1]; bj2[pos] = bj2[pos - 1]; --pos;
          }
          bv[pos] = v; bj2[pos] = j;
        }
      }
    }
    const float *m0 = mx + (size_t)bj2[0] * C_DIM, *m1 = mx + (size_t)bj2[1] * C_DIM;
    const float *m2 = mx + (size_t)bj2[2] * C_DIM, *m3 = mx + (size_t)bj2[3] * C_DIM;
    const float *m4 = mx + (size_t)bj2[4] * C_DIM, *m5 = mx + (size_t)bj2[5] * C_DIM;
    const float *m6 = mx + (size_t)bj2[6] * C_DIM, *m7 = mx + (size_t)bj2[7] * C_DIM;
    const float* xq = xbase + t;
    double d0 = 0, d1 = 0, d2 = 0, d3 = 0, d4 = 0, d5 = 0, d6 = 0, d7 = 0;
#pragma unroll 4
    for (int c = 0; c < C_DIM; ++c) {
      const double xv = (double)xq[(size_t)c * HW];
      double dd;
      dd = xv - (double)m0[c]; d0 = fma(dd, dd, d0);
      dd = xv - (double)m1[c]; d1 = fma(dd, dd, d1);
      dd = xv - (double)m2[c]; d2 = fma(dd, dd, d2);
      dd = xv - (double)m3[c]; d3 = fma(dd, dd, d3);
      dd = xv - (double)m4[c]; d4 = fma(dd, dd, d4);
      dd = xv - (double)m5[c]; d5 = fma(dd, dd, d5);
      dd = xv - (double)m6[c]; d6 = fma(dd, dd, d6);
      dd = xv - (double)m7[c]; d7 = fma(dd, dd, d7);
    }
    const double dv[8] = {d0, d1, d2, d3, d4, d5, d6, d7};
    const int jvv[8] = {bj2[0], bj2[1], bj2[2], bj2[3], bj2[4], bj2[5], bj2[6], bj2[7]};
    int labs[KSEL]; unsigned used = 0;
#pragma unroll
    for (int n = 0; n < KSEL; ++n) {
      double bd = 1e300; int bj = 0x7fffffff; int bk = 0;
#pragma unroll
      for (int k = 0; k < 8; ++k) {
        const bool avail = ((used >> k) & 1u) == 0u;
        if (avail && (dv[k] < bd || (dv[k] == bd && jvv[k] < bj))) {
          bd = dv[k]; bj = jvv[k]; bk = k;
        }
      }
      used |= (1u << bk);
      labs[n] = my[bj];
    }
    int bestLab = NUM_CLASSES, bestCnt = 0;
#pragma unroll
    for (int a = 0; a < KSEL; ++a) {
      int cnt = 0;
#pragma unroll
      for (int b2 = 0; b2 < KSEL; ++b2) cnt += (labs[b2] == labs[a]) ? 1 : 0;
      if (cnt > bestCnt || (cnt == bestCnt && labs[a] < bestLab)) { bestCnt = cnt; bestLab = labs[a]; }
    }
    float* ob = out + (size_t)bb * NUM_CLASSES * HW + hw0 + t;
#pragma unroll
    for (int cls = 0; cls < NUM_CLASSES; ++cls)
      ob[(size_t)cls * HW] = (cls == bestLab) ? 1.0f : 0.0f;
  }
}

extern "C" void kernel_launch(void* const* d_in, const int* in_sizes, int n_in,
                              void* d_out, int out_size, void* d_ws, size_t ws_size,
                              hipStream_t stream) {
  (void)in_sizes; (void)n_in; (void)out_size;
  const float* x  = (const float*)d_in[0];
  const float* mx = (const float*)d_in[2];   // d_in[1] (y) unused by reference
  const int*   my = (const int*)d_in[3];
  float* out = (float*)d_out;
  if (ws_size >= (size_t)WS_TOTAL) {
    float*  mn = (float*)((char*)d_ws + WS_MN_OFF);
    ushort* mw = (ushort*)((char*)d_ws + WS_MW_OFF);
    ushort* xb = (ushort*)((char*)d_ws + WS_XB_OFF);
    conv_m<<<MPAD / 64, 256, 0, stream>>>(mx, mw, mn);
    conv_x<<<32768 / 64, 256, 0, stream>>>(x, xb);
    knn_big<<<32768 / NQB, 512, 0, stream>>>(x, mx, mw, mn, xb, my, out);
  } else {
    knn_fb<<<32768 / FNQB, 256, 0, stream>>>(x, mx, my, out);
  }
}